// Round 6
// baseline (306.361 us; speedup 1.0000x reference)
//
#include <hip/hip_runtime.h>
#include <math.h>

#define N_WL 262144

#define T_REF 273.15
#define P_REF 101325.0
#define C_LIGHT 299792458.0
#define K_B 1.380649e-23
#define N_AVO 6.02214076e+23

// ws layout (floats):
//   [0:32)    h        (continuum hidden, silu'd)
//   [32:96)   m2       (mixing hidden state, silu'd)
//   [96:106)  nu0      voigt line centers
//   [106:116) isig     1/sigma
//   [116:126) y        gamma_L/sigma
//   [126:136) scale    conc*strength_T/(sigma*sqrt(pi))
//   [256 : 256+N_WL)          wsC  (continuum dot accumulator)
//   [256+N_WL : 256+2*N_WL)   wsM  (mixing dot accumulator)
#define WS_H     0
#define WS_M2    32
#define WS_NU0   96
#define WS_ISIG  106
#define WS_Y     116
#define WS_SCALE 126
#define WS_ACC   256

__constant__ float c_nu0[10]  = {254.0f, 280.0f, 310.0f, 940.0f, 1130.0f, 1380.0f, 1400.0f, 1600.0f, 2000.0f, 2700.0f};
__constant__ float c_str[10]  = {1.15e-17f, 5e-18f, 1.9e-19f, 2.5e-23f, 8.2e-24f, 1.8e-22f, 3.5e-25f, 7.8e-26f, 4.2e-24f, 1.2e-24f};
__constant__ float c_wid[10]  = {2.0f, 3.0f, 2.5f, 3.0f, 2.5f, 4.0f, 3.0f, 2.5f, 4.0f, 3.5f};
__constant__ float c_texp[10] = {0.05f, 0.04f, 0.03f, 0.4f, 0.35f, 0.45f, 0.5f, 0.48f, 0.52f, 0.49f};
__constant__ float c_mass[10] = {48.f, 48.f, 48.f, 18.f, 18.f, 18.f, 44.f, 44.f, 44.f, 44.f};
__constant__ int   c_cidx[10] = {0, 0, 0, 1, 1, 1, 2, 2, 2, 2};

__device__ __forceinline__ float siluf(float x)     { return x / (1.0f + __expf(-x)); }
__device__ __forceinline__ float sigmoidf(float x)  { return 1.0f / (1.0f + __expf(-x)); }
__device__ __forceinline__ float softplusf(float x) { return fmaxf(x, 0.0f) + log1pf(expf(-fabsf(x))); }

// Humlicek-style branched w(x,y) matching the reference (real part only).
__device__ __forceinline__ float voigt_w(float x, float y) {
    float ax = fabsf(x);
    float s  = ax + y;
    if (s >= 15.0f) {
        float ur = y * y - x * x;
        float ui = -2.0f * x * y;
        float dr = 0.5f + ur, di = ui;
        float nr = 0.5641896f * y, ni = 0.5641896f * (-x);
        float den = dr * dr + di * di;
        return (nr * dr + ni * di) / den;
    } else if (ax >= 5.5f) {
        float ur = y * y - x * x;
        float ui = -2.0f * x * y;
        float pr = 1.410474f + 0.5641896f * ur;
        float pi_ = 0.5641896f * ui;
        float tr = y, ti = -x;
        float nr = tr * pr - ti * pi_;
        float ni = tr * pi_ + ti * pr;
        float u2r = ur * ur - ui * ui;
        float u2i = 2.0f * ur * ui;
        float dr = 0.75f + 3.0f * ur + u2r;
        float di = 3.0f * ui + u2i;
        float den = dr * dr + di * di;
        return (nr * dr + ni * di) / den;
    } else {
        float x2 = x * x;
        return expf(-x2) * cosf(2.0f * x * y) * 0.5641895835477563f
             + (2.0f * y / 3.14159265358979f) * sinf(x2) / (x2 + y * y + 1e-10f);
    }
}

// ---- kernel 1: prep. block 0 = scalar setup; blocks 1..512 zero wsC/wsM ----
__global__ __launch_bounds__(256) void GasAbs_prep_kernel(
    const float* __restrict__ wl,
    const float* __restrict__ Tp, const float* __restrict__ Pp,
    const float* __restrict__ o3, const float* __restrict__ h2o, const float* __restrict__ co2,
    const float* __restrict__ mix_w1, const float* __restrict__ mix_b1,
    const float* __restrict__ mix_w2, const float* __restrict__ mix_b2,
    const float* __restrict__ cont_w1, const float* __restrict__ cont_b1,
    const float* __restrict__ cont_w2, const float* __restrict__ cont_b2,
    float* __restrict__ ws)
{
    const int t = threadIdx.x;

    if (blockIdx.x != 0) {
        // zero the two accumulator planes: 2*N_WL floats = 131072 float4s
        const int idx = (blockIdx.x - 1) * 256 + t;
        float4 z = {0.f, 0.f, 0.f, 0.f};
        reinterpret_cast<float4*>(ws + WS_ACC)[idx] = z;
        return;
    }

    __shared__ float s_nu0[10], s_isig[10], s_y[10], s_scale[10];
    __shared__ float s_h[32];
    __shared__ float s_feat[10];
    __shared__ float s_m1[64];

    if (t < 10) {
        const double T = (double)Tp[0];
        const double P = (double)Pp[0];
        const float cc3[3] = {o3[0], h2o[0], co2[0]};
        double nu0 = (double)c_nu0[t];
        double sT  = (double)c_str[t] * pow(T_REF / (T + 1e-12), (double)c_texp[t]);
        double gL  = (double)c_wid[t] * (P / (P_REF + 1e-12)) * sqrt(T_REF / (T + 1e-12));
        double gD  = nu0 / C_LIGHT * sqrt(2.0 * K_B * T * N_AVO / ((double)c_mass[t] + 1e-12));
        double sig = gD / (sqrt(2.0 * log(2.0)) + 1e-12);
        s_nu0[t]   = (float)nu0;
        s_isig[t]  = (float)(1.0 / (sig + 1e-12));
        s_y[t]     = (float)(gL / (sig + 1e-12));
        s_scale[t] = (float)((double)cc3[c_cidx[t]] * sT / (sig * sqrt(M_PI) + 1e-12));
        ws[WS_NU0  + t] = s_nu0[t];
        ws[WS_ISIG + t] = s_isig[t];
        ws[WS_Y    + t] = s_y[t];
        ws[WS_SCALE+ t] = s_scale[t];
    }
    if (t < 32) {
        const double T = (double)Tp[0];
        const double P = (double)Pp[0];
        float cf[5];
        cf[0] = (float)(T / (T_REF + 1e-12));
        cf[1] = (float)(P / (P_REF + 1e-12));
        cf[2] = h2o[0];
        cf[3] = 1.0f;
        cf[4] = 0.0f;
        float a = cont_b1[t];
        #pragma unroll
        for (int k = 0; k < 5; k++) a = fmaf(cf[k], cont_w1[k * 32 + t], a);
        s_h[t] = siluf(a);
        ws[WS_H + t] = s_h[t];
    }
    __syncthreads();

    if (t < 8) {
        float w = wl[t];
        float c = cont_b2[t];
        #pragma unroll
        for (int j = 0; j < 32; j++) c = fmaf(s_h[j], cont_w2[(size_t)j * N_WL + t], c);
        float cross = softplusf(c);
        #pragma unroll
        for (int l = 0; l < 10; l++) {
            float x = (w - s_nu0[l]) * s_isig[l];
            cross = fmaf(s_scale[l], voigt_w(x, s_y[l]), cross);
        }
        s_feat[2 + t] = cross;
    }
    if (t == 0) {
        const double T = (double)Tp[0];
        const double P = (double)Pp[0];
        s_feat[0] = (float)(T / (T_REF + 1e-12));
        s_feat[1] = (float)(P / (P_REF + 1e-12));
    }
    __syncthreads();

    if (t < 64) {
        float a = mix_b1[t];
        #pragma unroll
        for (int k = 0; k < 10; k++) a = fmaf(s_feat[k], mix_w1[k * 64 + t], a);
        s_m1[t] = siluf(a);
    }
    __syncthreads();

    if (t < 64) {
        float a = mix_b2[t];
        #pragma unroll
        for (int k = 0; k < 64; k++) a = fmaf(s_m1[k], mix_w2[k * 64 + t], a);
        ws[WS_M2 + t] = siluf(a);
    }
}

// ---- kernel 2: accumulate. One block = (4-row group) x (2048-elem chunk).
// Reads are long contiguous row segments (8 KB/row/block) -- the linear
// pattern proven at 6.5 TB/s on this chip -- and 12288 short-lived waves
// give raw TLP no matter how the compiler places waits. Partials for the
// 4 rows combine in registers; one atomicAdd per element per block.
#define RPB   4      // rows per block
#define CHUNK 2048   // elements per block
__global__ __launch_bounds__(256) void GasAbs_acc_kernel(
    const float* __restrict__ cont_w2,
    const float* __restrict__ mix_w3,
    float* __restrict__ ws)
{
    // grid = 24 groups * 128 chunks; bid = g*128 + c so consecutive blocks
    // stream consecutive chunks of the same row-group (linear footprint).
    const int g = blockIdx.x >> 7;
    const int c = blockIdx.x & 127;
    const int base = c * CHUNK + threadIdx.x * 8;   // 8 contiguous elems/thread

    const float* W;
    const float* coef;
    float* plane;
    int row0;
    if (g < 8) {            // continuum rows 0..31
        row0  = g * RPB;
        W     = cont_w2;
        coef  = ws + WS_H + row0;
        plane = ws + WS_ACC;
    } else {                // mixing rows 0..63
        row0  = (g - 8) * RPB;
        W     = mix_w3;
        coef  = ws + WS_M2 + row0;
        plane = ws + WS_ACC + N_WL;
    }

    const float k0 = coef[0], k1 = coef[1], k2 = coef[2], k3 = coef[3];

    // 8 independent float4 loads (4 rows x 2), then consume.
    float4 v0[RPB], v1[RPB];
    #pragma unroll
    for (int r = 0; r < RPB; ++r) {
        const float* p = W + (size_t)(row0 + r) * N_WL + base;
        v0[r] = *reinterpret_cast<const float4*>(p);
        v1[r] = *reinterpret_cast<const float4*>(p + 4);
    }

    float4 a0 = {0.f,0.f,0.f,0.f}, a1 = {0.f,0.f,0.f,0.f};
    const float kk[RPB] = {k0, k1, k2, k3};
    #pragma unroll
    for (int r = 0; r < RPB; ++r) {
        a0.x = fmaf(kk[r], v0[r].x, a0.x);
        a0.y = fmaf(kk[r], v0[r].y, a0.y);
        a0.z = fmaf(kk[r], v0[r].z, a0.z);
        a0.w = fmaf(kk[r], v0[r].w, a0.w);
        a1.x = fmaf(kk[r], v1[r].x, a1.x);
        a1.y = fmaf(kk[r], v1[r].y, a1.y);
        a1.z = fmaf(kk[r], v1[r].z, a1.z);
        a1.w = fmaf(kk[r], v1[r].w, a1.w);
    }

    float* d = plane + base;
    atomicAdd(d + 0, a0.x);
    atomicAdd(d + 1, a0.y);
    atomicAdd(d + 2, a0.z);
    atomicAdd(d + 3, a0.w);
    atomicAdd(d + 4, a1.x);
    atomicAdd(d + 5, a1.y);
    atomicAdd(d + 6, a1.z);
    atomicAdd(d + 7, a1.w);
}

// ---- kernel 3: finish. Elementwise: softplus(bias+accC) + voigt, gate. ----
__global__ __launch_bounds__(256) void GasAbs_finish_kernel(
    const float* __restrict__ wl,
    const float* __restrict__ mix_b3,
    const float* __restrict__ cont_b2,
    const float* __restrict__ ws,
    float* __restrict__ out)
{
    __shared__ float sp[40];   // nu0[10], isig[10], y[10], scale[10]
    const int t = threadIdx.x;
    if (t < 40) sp[t] = ws[WS_NU0 + t];
    __syncthreads();

    const int i0 = (blockIdx.x * 256 + t) * 4;

    const float4 w4  = *reinterpret_cast<const float4*>(wl + i0);
    const float4 bc4 = *reinterpret_cast<const float4*>(cont_b2 + i0);
    const float4 bm4 = *reinterpret_cast<const float4*>(mix_b3 + i0);
    const float4 aC  = *reinterpret_cast<const float4*>(ws + WS_ACC + i0);
    const float4 aM  = *reinterpret_cast<const float4*>(ws + WS_ACC + N_WL + i0);

    float cr0 = softplusf(bc4.x + aC.x);
    float cr1 = softplusf(bc4.y + aC.y);
    float cr2 = softplusf(bc4.z + aC.z);
    float cr3 = softplusf(bc4.w + aC.w);

    #pragma unroll
    for (int l = 0; l < 10; l++) {
        const float nu0 = sp[l], isig = sp[10 + l], yy = sp[20 + l], sc = sp[30 + l];
        cr0 = fmaf(sc, voigt_w((w4.x - nu0) * isig, yy), cr0);
        cr1 = fmaf(sc, voigt_w((w4.y - nu0) * isig, yy), cr1);
        cr2 = fmaf(sc, voigt_w((w4.z - nu0) * isig, yy), cr2);
        cr3 = fmaf(sc, voigt_w((w4.w - nu0) * isig, yy), cr3);
    }

    float4 o;
    o.x = cr0 * (0.95f + 0.1f * sigmoidf(bm4.x + aM.x));
    o.y = cr1 * (0.95f + 0.1f * sigmoidf(bm4.y + aM.y));
    o.z = cr2 * (0.95f + 0.1f * sigmoidf(bm4.z + aM.z));
    o.w = cr3 * (0.95f + 0.1f * sigmoidf(bm4.w + aM.w));
    *reinterpret_cast<float4*>(out + i0) = o;
}

extern "C" void kernel_launch(void* const* d_in, const int* in_sizes, int n_in,
                              void* d_out, int out_size, void* d_ws, size_t ws_size,
                              hipStream_t stream) {
    const float* wl      = (const float*)d_in[0];
    const float* Tp      = (const float*)d_in[1];
    const float* Pp      = (const float*)d_in[2];
    const float* o3      = (const float*)d_in[3];
    const float* h2o     = (const float*)d_in[4];
    const float* co2     = (const float*)d_in[5];
    const float* mix_w1  = (const float*)d_in[6];
    const float* mix_b1  = (const float*)d_in[7];
    const float* mix_w2  = (const float*)d_in[8];
    const float* mix_b2  = (const float*)d_in[9];
    const float* mix_w3  = (const float*)d_in[10];
    const float* mix_b3  = (const float*)d_in[11];
    const float* cont_w1 = (const float*)d_in[12];
    const float* cont_b1 = (const float*)d_in[13];
    const float* cont_w2 = (const float*)d_in[14];
    const float* cont_b2 = (const float*)d_in[15];
    float* ws  = (float*)d_ws;
    float* out = (float*)d_out;

    // prep: block 0 = scalar setup; 512 blocks zero the 2 MB of accumulators
    GasAbs_prep_kernel<<<513, 256, 0, stream>>>(
        wl, Tp, Pp, o3, h2o, co2,
        mix_w1, mix_b1, mix_w2, mix_b2,
        cont_w1, cont_b1, cont_w2, cont_b2, ws);

    // accumulate: 24 row-groups x 128 chunks, linear row-segment reads
    GasAbs_acc_kernel<<<24 * 128, 256, 0, stream>>>(cont_w2, mix_w3, ws);

    // finish: elementwise voigt + activations
    GasAbs_finish_kernel<<<N_WL / (256 * 4), 256, 0, stream>>>(
        wl, mix_b3, cont_b2, ws, out);
}

// Round 7
// 164.655 us; speedup vs baseline: 1.8606x; 1.8606x over previous
//
#include <hip/hip_runtime.h>
#include <math.h>

#define N_WL 262144

#define T_REF 273.15
#define P_REF 101325.0
#define C_LIGHT 299792458.0
#define K_B 1.380649e-23
#define N_AVO 6.02214076e+23

// ws layout (floats):
//   [0:32)    h        (continuum hidden, silu'd)
//   [32:96)   m2       (mixing hidden state, silu'd)
//   [96:106)  nu0      [106:116) isig   [116:126) y   [126:136) scale
//   [256 + g*N_WL), g=0..11 : partial planes (g<4: cont, g>=4: mix)
#define WS_H     0
#define WS_M2    32
#define WS_NU0   96
#define WS_ISIG  106
#define WS_Y     116
#define WS_SCALE 126
#define WS_ACC   256

__constant__ float c_nu0[10]  = {254.0f, 280.0f, 310.0f, 940.0f, 1130.0f, 1380.0f, 1400.0f, 1600.0f, 2000.0f, 2700.0f};
__constant__ float c_str[10]  = {1.15e-17f, 5e-18f, 1.9e-19f, 2.5e-23f, 8.2e-24f, 1.8e-22f, 3.5e-25f, 7.8e-26f, 4.2e-24f, 1.2e-24f};
__constant__ float c_wid[10]  = {2.0f, 3.0f, 2.5f, 3.0f, 2.5f, 4.0f, 3.0f, 2.5f, 4.0f, 3.5f};
__constant__ float c_texp[10] = {0.05f, 0.04f, 0.03f, 0.4f, 0.35f, 0.45f, 0.5f, 0.48f, 0.52f, 0.49f};
__constant__ float c_mass[10] = {48.f, 48.f, 48.f, 18.f, 18.f, 18.f, 44.f, 44.f, 44.f, 44.f};
__constant__ int   c_cidx[10] = {0, 0, 0, 1, 1, 1, 2, 2, 2, 2};

__device__ __forceinline__ float siluf(float x)     { return x / (1.0f + __expf(-x)); }
__device__ __forceinline__ float sigmoidf(float x)  { return 1.0f / (1.0f + __expf(-x)); }
__device__ __forceinline__ float softplusf(float x) { return fmaxf(x, 0.0f) + log1pf(expf(-fabsf(x))); }

// Humlicek-style branched w(x,y) matching the reference (real part only).
__device__ __forceinline__ float voigt_w(float x, float y) {
    float ax = fabsf(x);
    float s  = ax + y;
    if (s >= 15.0f) {
        float ur = y * y - x * x;
        float ui = -2.0f * x * y;
        float dr = 0.5f + ur, di = ui;
        float nr = 0.5641896f * y, ni = 0.5641896f * (-x);
        float den = dr * dr + di * di;
        return (nr * dr + ni * di) / den;
    } else if (ax >= 5.5f) {
        float ur = y * y - x * x;
        float ui = -2.0f * x * y;
        float pr = 1.410474f + 0.5641896f * ur;
        float pi_ = 0.5641896f * ui;
        float tr = y, ti = -x;
        float nr = tr * pr - ti * pi_;
        float ni = tr * pi_ + ti * pr;
        float u2r = ur * ur - ui * ui;
        float u2i = 2.0f * ur * ui;
        float dr = 0.75f + 3.0f * ur + u2r;
        float di = 3.0f * ui + u2i;
        float den = dr * dr + di * di;
        return (nr * dr + ni * di) / den;
    } else {
        float x2 = x * x;
        return expf(-x2) * cosf(2.0f * x * y) * 0.5641895835477563f
             + (2.0f * y / 3.14159265358979f) * sinf(x2) / (x2 + y * y + 1e-10f);
    }
}

// ---- kernel 1: prep (1 block). Scalar setup -> ws header. ----
__global__ __launch_bounds__(256) void GasAbs_prep_kernel(
    const float* __restrict__ wl,
    const float* __restrict__ Tp, const float* __restrict__ Pp,
    const float* __restrict__ o3, const float* __restrict__ h2o, const float* __restrict__ co2,
    const float* __restrict__ mix_w1, const float* __restrict__ mix_b1,
    const float* __restrict__ mix_w2, const float* __restrict__ mix_b2,
    const float* __restrict__ cont_w1, const float* __restrict__ cont_b1,
    const float* __restrict__ cont_w2, const float* __restrict__ cont_b2,
    float* __restrict__ ws)
{
    const int t = threadIdx.x;

    __shared__ float s_nu0[10], s_isig[10], s_y[10], s_scale[10];
    __shared__ float s_h[32];
    __shared__ float s_feat[10];
    __shared__ float s_m1[64];

    if (t < 10) {
        const double T = (double)Tp[0];
        const double P = (double)Pp[0];
        const float cc3[3] = {o3[0], h2o[0], co2[0]};
        double nu0 = (double)c_nu0[t];
        double sT  = (double)c_str[t] * pow(T_REF / (T + 1e-12), (double)c_texp[t]);
        double gL  = (double)c_wid[t] * (P / (P_REF + 1e-12)) * sqrt(T_REF / (T + 1e-12));
        double gD  = nu0 / C_LIGHT * sqrt(2.0 * K_B * T * N_AVO / ((double)c_mass[t] + 1e-12));
        double sig = gD / (sqrt(2.0 * log(2.0)) + 1e-12);
        s_nu0[t]   = (float)nu0;
        s_isig[t]  = (float)(1.0 / (sig + 1e-12));
        s_y[t]     = (float)(gL / (sig + 1e-12));
        s_scale[t] = (float)((double)cc3[c_cidx[t]] * sT / (sig * sqrt(M_PI) + 1e-12));
        ws[WS_NU0  + t] = s_nu0[t];
        ws[WS_ISIG + t] = s_isig[t];
        ws[WS_Y    + t] = s_y[t];
        ws[WS_SCALE+ t] = s_scale[t];
    }
    if (t < 32) {
        const double T = (double)Tp[0];
        const double P = (double)Pp[0];
        float cf[5];
        cf[0] = (float)(T / (T_REF + 1e-12));
        cf[1] = (float)(P / (P_REF + 1e-12));
        cf[2] = h2o[0];
        cf[3] = 1.0f;
        cf[4] = 0.0f;
        float a = cont_b1[t];
        #pragma unroll
        for (int k = 0; k < 5; k++) a = fmaf(cf[k], cont_w1[k * 32 + t], a);
        s_h[t] = siluf(a);
        ws[WS_H + t] = s_h[t];
    }
    __syncthreads();

    if (t < 8) {
        float w = wl[t];
        float c = cont_b2[t];
        #pragma unroll
        for (int j = 0; j < 32; j++) c = fmaf(s_h[j], cont_w2[(size_t)j * N_WL + t], c);
        float cross = softplusf(c);
        #pragma unroll
        for (int l = 0; l < 10; l++) {
            float x = (w - s_nu0[l]) * s_isig[l];
            cross = fmaf(s_scale[l], voigt_w(x, s_y[l]), cross);
        }
        s_feat[2 + t] = cross;
    }
    if (t == 0) {
        const double T = (double)Tp[0];
        const double P = (double)Pp[0];
        s_feat[0] = (float)(T / (T_REF + 1e-12));
        s_feat[1] = (float)(P / (P_REF + 1e-12));
    }
    __syncthreads();

    if (t < 64) {
        float a = mix_b1[t];
        #pragma unroll
        for (int k = 0; k < 10; k++) a = fmaf(s_feat[k], mix_w1[k * 64 + t], a);
        s_m1[t] = siluf(a);
    }
    __syncthreads();

    if (t < 64) {
        float a = mix_b2[t];
        #pragma unroll
        for (int k = 0; k < 64; k++) a = fmaf(s_m1[k], mix_w2[k * 64 + t], a);
        ws[WS_M2 + t] = siluf(a);
    }
}

// ---- kernel 2: accumulate into EXCLUSIVE partial planes (no atomics). ----
// Grid = 12 groups x 256 chunks. Group g owns 8 rows (g<4: cont_w2 rows
// 8g..8g+7; g>=4: mix_w3 rows 8(g-4)..). Block = 256 threads x 1 float4 x
// 8 rows: every load instruction covers a dense 1 KB row segment (the
// pattern m13's 6.3 TB/s copy uses), 8 independent loads/thread, and the
// block's single float4 partial store goes to its own plane ws[g] --
// plain coalesced stores, zero cross-block contention (R6's 201 MB
// atomic write-amplification eliminated).
__global__ __launch_bounds__(256) void GasAbs_acc_kernel(
    const float* __restrict__ cont_w2,
    const float* __restrict__ mix_w3,
    float* __restrict__ ws)
{
    const int t = threadIdx.x;
    const int g = blockIdx.x >> 8;     // 0..11
    const int c = blockIdx.x & 255;    // chunk
    const int base = c * 1024 + t * 4;

    const float* W;
    const float* coef;
    int row0;
    if (g < 4) {
        row0 = g * 8;
        W    = cont_w2;
        coef = ws + WS_H + row0;
    } else {
        row0 = (g - 4) * 8;
        W    = mix_w3;
        coef = ws + WS_M2 + row0;
    }

    float4 v[8];
    #pragma unroll
    for (int r = 0; r < 8; ++r)
        v[r] = *reinterpret_cast<const float4*>(W + (size_t)(row0 + r) * N_WL + base);

    float4 a = {0.f, 0.f, 0.f, 0.f};
    #pragma unroll
    for (int r = 0; r < 8; ++r) {
        const float k = coef[r];
        a.x = fmaf(k, v[r].x, a.x);
        a.y = fmaf(k, v[r].y, a.y);
        a.z = fmaf(k, v[r].z, a.z);
        a.w = fmaf(k, v[r].w, a.w);
    }

    *reinterpret_cast<float4*>(ws + WS_ACC + (size_t)g * N_WL + base) = a;
}

// ---- kernel 3: finish. Sum planes, biases, voigt, gate. ----
__global__ __launch_bounds__(256) void GasAbs_finish_kernel(
    const float* __restrict__ wl,
    const float* __restrict__ mix_b3,
    const float* __restrict__ cont_b2,
    const float* __restrict__ ws,
    float* __restrict__ out)
{
    __shared__ float sp[40];   // nu0[10], isig[10], y[10], scale[10]
    const int t = threadIdx.x;
    if (t < 40) sp[t] = ws[WS_NU0 + t];
    __syncthreads();

    const int i0 = (blockIdx.x * 256 + t) * 4;

    // 12 independent plane loads + 3 scalar-stream loads.
    float4 p[12];
    #pragma unroll
    for (int g = 0; g < 12; ++g)
        p[g] = *reinterpret_cast<const float4*>(ws + WS_ACC + (size_t)g * N_WL + i0);

    const float4 w4  = *reinterpret_cast<const float4*>(wl + i0);
    const float4 bc4 = *reinterpret_cast<const float4*>(cont_b2 + i0);
    const float4 bm4 = *reinterpret_cast<const float4*>(mix_b3 + i0);

    float4 aC = bc4, aM = bm4;
    #pragma unroll
    for (int g = 0; g < 4; ++g) {
        aC.x += p[g].x; aC.y += p[g].y; aC.z += p[g].z; aC.w += p[g].w;
    }
    #pragma unroll
    for (int g = 4; g < 12; ++g) {
        aM.x += p[g].x; aM.y += p[g].y; aM.z += p[g].z; aM.w += p[g].w;
    }

    float cr0 = softplusf(aC.x);
    float cr1 = softplusf(aC.y);
    float cr2 = softplusf(aC.z);
    float cr3 = softplusf(aC.w);

    #pragma unroll
    for (int l = 0; l < 10; l++) {
        const float nu0 = sp[l], isig = sp[10 + l], yy = sp[20 + l], sc = sp[30 + l];
        cr0 = fmaf(sc, voigt_w((w4.x - nu0) * isig, yy), cr0);
        cr1 = fmaf(sc, voigt_w((w4.y - nu0) * isig, yy), cr1);
        cr2 = fmaf(sc, voigt_w((w4.z - nu0) * isig, yy), cr2);
        cr3 = fmaf(sc, voigt_w((w4.w - nu0) * isig, yy), cr3);
    }

    float4 o;
    o.x = cr0 * (0.95f + 0.1f * sigmoidf(aM.x));
    o.y = cr1 * (0.95f + 0.1f * sigmoidf(aM.y));
    o.z = cr2 * (0.95f + 0.1f * sigmoidf(aM.z));
    o.w = cr3 * (0.95f + 0.1f * sigmoidf(aM.w));
    *reinterpret_cast<float4*>(out + i0) = o;
}

extern "C" void kernel_launch(void* const* d_in, const int* in_sizes, int n_in,
                              void* d_out, int out_size, void* d_ws, size_t ws_size,
                              hipStream_t stream) {
    const float* wl      = (const float*)d_in[0];
    const float* Tp      = (const float*)d_in[1];
    const float* Pp      = (const float*)d_in[2];
    const float* o3      = (const float*)d_in[3];
    const float* h2o     = (const float*)d_in[4];
    const float* co2     = (const float*)d_in[5];
    const float* mix_w1  = (const float*)d_in[6];
    const float* mix_b1  = (const float*)d_in[7];
    const float* mix_w2  = (const float*)d_in[8];
    const float* mix_b2  = (const float*)d_in[9];
    const float* mix_w3  = (const float*)d_in[10];
    const float* mix_b3  = (const float*)d_in[11];
    const float* cont_w1 = (const float*)d_in[12];
    const float* cont_b1 = (const float*)d_in[13];
    const float* cont_w2 = (const float*)d_in[14];
    const float* cont_b2 = (const float*)d_in[15];
    float* ws  = (float*)d_ws;
    float* out = (float*)d_out;

    // prep: scalar setup only (partial planes are fully overwritten by acc)
    GasAbs_prep_kernel<<<1, 256, 0, stream>>>(
        wl, Tp, Pp, o3, h2o, co2,
        mix_w1, mix_b1, mix_w2, mix_b2,
        cont_w1, cont_b1, cont_w2, cont_b2, ws);

    // accumulate: 12 row-groups x 256 chunks, dense 1 KB per load instr
    GasAbs_acc_kernel<<<12 * 256, 256, 0, stream>>>(cont_w2, mix_w3, ws);

    // finish: plane reduction + voigt + activations
    GasAbs_finish_kernel<<<N_WL / (256 * 4), 256, 0, stream>>>(
        wl, mix_b3, cont_b2, ws, out);
}

// Round 8
// 151.698 us; speedup vs baseline: 2.0196x; 1.0854x over previous
//
#include <hip/hip_runtime.h>
#include <math.h>

#define N_WL 262144

#define T_REF 273.15
#define P_REF 101325.0
#define C_LIGHT 299792458.0
#define K_B 1.380649e-23
#define N_AVO 6.02214076e+23

__constant__ float c_nu0[10]  = {254.0f, 280.0f, 310.0f, 940.0f, 1130.0f, 1380.0f, 1400.0f, 1600.0f, 2000.0f, 2700.0f};
__constant__ float c_str[10]  = {1.15e-17f, 5e-18f, 1.9e-19f, 2.5e-23f, 8.2e-24f, 1.8e-22f, 3.5e-25f, 7.8e-26f, 4.2e-24f, 1.2e-24f};
__constant__ float c_wid[10]  = {2.0f, 3.0f, 2.5f, 3.0f, 2.5f, 4.0f, 3.0f, 2.5f, 4.0f, 3.5f};
__constant__ float c_texp[10] = {0.05f, 0.04f, 0.03f, 0.4f, 0.35f, 0.45f, 0.5f, 0.48f, 0.52f, 0.49f};
__constant__ float c_mass[10] = {48.f, 48.f, 48.f, 18.f, 18.f, 18.f, 44.f, 44.f, 44.f, 44.f};
__constant__ int   c_cidx[10] = {0, 0, 0, 1, 1, 1, 2, 2, 2, 2};

__device__ __forceinline__ float siluf(float x)     { return x / (1.0f + __expf(-x)); }
__device__ __forceinline__ float sigmoidf(float x)  { return 1.0f / (1.0f + __expf(-x)); }
__device__ __forceinline__ float softplusf(float x) { return fmaxf(x, 0.0f) + log1pf(expf(-fabsf(x))); }

// Humlicek-style branched w(x,y) matching the reference (real part only).
// At runtime physics (y = gamma_L/sigma ~ 1e5) branch 1 is always taken,
// uniformly across the wave -> no divergence, no transcendentals.
__device__ __forceinline__ float voigt_w(float x, float y) {
    float ax = fabsf(x);
    float s  = ax + y;
    if (s >= 15.0f) {
        float ur = y * y - x * x;
        float ui = -2.0f * x * y;
        float dr = 0.5f + ur, di = ui;
        float nr = 0.5641896f * y, ni = 0.5641896f * (-x);
        float den = dr * dr + di * di;
        return (nr * dr + ni * di) / den;
    } else if (ax >= 5.5f) {
        float ur = y * y - x * x;
        float ui = -2.0f * x * y;
        float pr = 1.410474f + 0.5641896f * ur;
        float pi_ = 0.5641896f * ui;
        float tr = y, ti = -x;
        float nr = tr * pr - ti * pi_;
        float ni = tr * pi_ + ti * pr;
        float u2r = ur * ur - ui * ui;
        float u2i = 2.0f * ur * ui;
        float dr = 0.75f + 3.0f * ur + u2r;
        float di = 3.0f * ui + u2i;
        float den = dr * dr + di * di;
        return (nr * dr + ni * di) / den;
    } else {
        float x2 = x * x;
        return expf(-x2) * cosf(2.0f * x * y) * 0.5641895835477563f
             + (2.0f * y / 3.14159265358979f) * sinf(x2) / (x2 + y * y + 1e-10f);
    }
}

// ---------------- single fused kernel (session champion, R3) ----------------
// Phase A: every block redundantly computes the scalar setup (identical
//          inputs -> identical results; weight reads are L2 hits).
// Phase B: 1 wavelength/thread (1024 blocks = 16 waves/CU), the 96 weight
//          rows (32 cont_w2 + 64 mix_w3) streamed through one 16-deep
//          rotating register pipeline with asm-memory fences every 8 rows.
// Measured: 41-42 us kernel, ~51 MB compulsory HBM fetch -- at the
// structural floor (harness re-poison + read-side cap, see ledger R0-R7).
__global__ __launch_bounds__(256) void GasAbs_fused_kernel(
    const float* __restrict__ wl,
    const float* __restrict__ Tp, const float* __restrict__ Pp,
    const float* __restrict__ o3, const float* __restrict__ h2o, const float* __restrict__ co2,
    const float* __restrict__ mix_w1, const float* __restrict__ mix_b1,
    const float* __restrict__ mix_w2, const float* __restrict__ mix_b2,
    const float* __restrict__ mix_w3, const float* __restrict__ mix_b3,
    const float* __restrict__ cont_w1, const float* __restrict__ cont_b1,
    const float* __restrict__ cont_w2, const float* __restrict__ cont_b2,
    float* __restrict__ out)
{
    __shared__ float s_nu0[10], s_isig[10], s_y[10], s_scale[10];
    __shared__ float s_h[32];
    __shared__ float s_feat[10];
    __shared__ float s_m1[64];
    __shared__ float s_m2[64];

    const int t = threadIdx.x;

    // ---- Phase A: redundant per-block scalar setup ----
    if (t < 10) {
        const double T = (double)Tp[0];
        const double P = (double)Pp[0];
        const float cc3[3] = {o3[0], h2o[0], co2[0]};
        double nu0 = (double)c_nu0[t];
        double sT  = (double)c_str[t] * pow(T_REF / (T + 1e-12), (double)c_texp[t]);
        double gL  = (double)c_wid[t] * (P / (P_REF + 1e-12)) * sqrt(T_REF / (T + 1e-12));
        double gD  = nu0 / C_LIGHT * sqrt(2.0 * K_B * T * N_AVO / ((double)c_mass[t] + 1e-12));
        double sig = gD / (sqrt(2.0 * log(2.0)) + 1e-12);
        s_nu0[t]   = (float)nu0;
        s_isig[t]  = (float)(1.0 / (sig + 1e-12));
        s_y[t]     = (float)(gL / (sig + 1e-12));
        s_scale[t] = (float)((double)cc3[c_cidx[t]] * sT / (sig * sqrt(M_PI) + 1e-12));
    }
    if (t < 32) {
        const double T = (double)Tp[0];
        const double P = (double)Pp[0];
        float cf[5];
        cf[0] = (float)(T / (T_REF + 1e-12));
        cf[1] = (float)(P / (P_REF + 1e-12));
        cf[2] = h2o[0];
        cf[3] = 1.0f;
        cf[4] = 0.0f;
        float a = cont_b1[t];
        #pragma unroll
        for (int k = 0; k < 5; k++) a = fmaf(cf[k], cont_w1[k * 32 + t], a);
        s_h[t] = siluf(a);
    }
    __syncthreads();

    if (t < 8) {
        float w = wl[t];
        float c = cont_b2[t];
        #pragma unroll
        for (int j = 0; j < 32; j++) c = fmaf(s_h[j], cont_w2[(size_t)j * N_WL + t], c);
        float cross = softplusf(c);
        #pragma unroll
        for (int l = 0; l < 10; l++) {
            float x = (w - s_nu0[l]) * s_isig[l];
            cross = fmaf(s_scale[l], voigt_w(x, s_y[l]), cross);
        }
        s_feat[2 + t] = cross;
    }
    if (t == 0) {
        const double T = (double)Tp[0];
        const double P = (double)Pp[0];
        s_feat[0] = (float)(T / (T_REF + 1e-12));
        s_feat[1] = (float)(P / (P_REF + 1e-12));
    }
    __syncthreads();

    if (t < 64) {
        float a = mix_b1[t];
        #pragma unroll
        for (int k = 0; k < 10; k++) a = fmaf(s_feat[k], mix_w1[k * 64 + t], a);
        s_m1[t] = siluf(a);
    }
    __syncthreads();

    if (t < 64) {
        float a = mix_b2[t];
        #pragma unroll
        for (int k = 0; k < 64; k++) a = fmaf(s_m1[k], mix_w2[k * 64 + t], a);
        s_m2[t] = siluf(a);
    }
    __syncthreads();

    // ---- Phase B: 1 element/thread, unified 96-row 16-deep pipeline ----
    const int i = blockIdx.x * 256 + t;
    const float* __restrict__ wp = cont_w2 + i;   // 32 rows, stride N_WL
    const float* __restrict__ mp = mix_w3  + i;   // 64 rows, stride N_WL

    // oldest loads first: scalars this thread needs
    const float wv = wl[i];
    const float bc = cont_b2[i];
    const float bm = mix_b3[i];

    // prologue: fill the 16-slot pipeline (rows 0..15 of cont_w2)
    float buf[16];
    #pragma unroll
    for (int k = 0; k < 16; k++)
        buf[k] = wp[(size_t)k * N_WL];
    asm volatile("" ::: "memory");   // pin: prologue issues stay above voigt

    // Voigt line sum runs under the 16 in-flight loads (pure VALU).
    float vsum = 0.0f;
    #pragma unroll
    for (int l = 0; l < 10; l++) {
        const float x = (wv - s_nu0[l]) * s_isig[l];
        vsum = fmaf(s_scale[l], voigt_w(x, s_y[l]), vsum);
    }

    float acc_c = bc;
    float acc_m = bm;

    // 96 rows: consume row k, immediately re-issue row k+16 into the freed
    // slot. Fences every 8 rows pin cross-group order.
    #pragma unroll
    for (int g = 0; g < 12; g++) {
        #pragma unroll
        for (int u = 0; u < 8; u++) {
            const int k = g * 8 + u;
            const float v = buf[k & 15];
            if (k < 32) acc_c = fmaf(s_h[k],      v, acc_c);
            else        acc_m = fmaf(s_m2[k - 32], v, acc_m);
            const int kn = k + 16;
            if (kn < 96)
                buf[k & 15] = (kn < 32) ? wp[(size_t)kn * N_WL]
                                        : mp[(size_t)(kn - 32) * N_WL];
        }
        asm volatile("" ::: "memory");
    }

    const float cross = softplusf(acc_c) + vsum;
    out[i] = cross * (0.95f + 0.1f * sigmoidf(acc_m));
}

extern "C" void kernel_launch(void* const* d_in, const int* in_sizes, int n_in,
                              void* d_out, int out_size, void* d_ws, size_t ws_size,
                              hipStream_t stream) {
    const float* wl      = (const float*)d_in[0];
    const float* Tp      = (const float*)d_in[1];
    const float* Pp      = (const float*)d_in[2];
    const float* o3      = (const float*)d_in[3];
    const float* h2o     = (const float*)d_in[4];
    const float* co2     = (const float*)d_in[5];
    const float* mix_w1  = (const float*)d_in[6];
    const float* mix_b1  = (const float*)d_in[7];
    const float* mix_w2  = (const float*)d_in[8];
    const float* mix_b2  = (const float*)d_in[9];
    const float* mix_w3  = (const float*)d_in[10];
    const float* mix_b3  = (const float*)d_in[11];
    const float* cont_w1 = (const float*)d_in[12];
    const float* cont_b1 = (const float*)d_in[13];
    const float* cont_w2 = (const float*)d_in[14];
    const float* cont_b2 = (const float*)d_in[15];
    float* out = (float*)d_out;

    const int threads = 256;
    const int blocks  = N_WL / threads;   // 1024 blocks, 1 wl/thread
    GasAbs_fused_kernel<<<blocks, threads, 0, stream>>>(
        wl, Tp, Pp, o3, h2o, co2,
        mix_w1, mix_b1, mix_w2, mix_b2, mix_w3, mix_b3,
        cont_w1, cont_b1, cont_w2, cont_b2, out);
}